// Round 12
// baseline (941.053 us; speedup 1.0000x reference)
//
#include <hip/hip_runtime.h>
#include <math.h>

#define NXC 32768
#define NVC 16384
#define OUTWC (NXC + 64 + NVC)

static constexpr float DXf   = 1.0f/32768.0f;
static constexpr float DVf   = 16.0f/16384.0f;
static constexpr float DTf   = 1e-3f;
static constexpr float VMAXf = 8.0f;
static constexpr float INV2PI= 0.15915494309189535f;

#define PS_V 16576
#define PS_X 8256
#define PS_E 8192

// ---------------- gshape ----------------
__global__ __launch_bounds__(1024) void k_gshape(float* __restrict__ g){
  __shared__ float red[1024];
  int t = threadIdx.x;
  float s = 0.f;
  for (int i = t; i < NXC; i += 1024){
    float x = (i + 0.5f)*DXf - 0.5f;
    float xx = x*10.0f;
    float gv = expf(-0.5f*xx*xx);
    g[i] = gv; s += gv;
  }
  red[t] = s; __syncthreads();
  for (int o = 512; o > 0; o >>= 1){ if (t < o) red[t] += red[t+o]; __syncthreads(); }
  float norm = 1.0f/(red[0]*DXf);
  for (int i = t; i < NXC; i += 1024) g[i] *= norm;
}

// ---------------- V stats ----------------
__global__ __launch_bounds__(256) void k_vstatsf(const float* __restrict__ V0, const float* __restrict__ V1,
                                                 float* __restrict__ part){
  __shared__ float Vt[64][67];
  int sp = blockIdx.y;
  const float* V = sp ? V1 : V0;
  float Amax = sp ? 1836.0f : 1.0f;
  int blk = blockIdx.x;
  int nbk = gridDim.x;
  int chunk = NVC/nbk;
  int c0b = blk*chunk;
  int tid = threadIdx.x;
  int ta = tid >> 4, tb = tid & 15;
  int a0 = ta*4, b0 = tb*4;
  float acc0[4][4]={{0}}, acc1[4][4]={{0}}, accp[4][4]={{0}}, accm[4][4]={{0}};
  float vsv[4]={0,0,0,0}, vvm[4]={0,0,0,0}, vwv[4]={0,0,0,0};
  float fm = sqrtf(Amax*INV2PI);
  for (int t0 = 0; t0 < chunk; t0 += 64){
    int c0 = c0b + t0;
    for (int i = tid; i < 64*65; i += 256){
      int r = i/65, cc = i%65;
      int c = c0 - 1 + cc;
      Vt[r][cc] = (c >= 0 && c < NVC) ? V[(size_t)r*NVC + c] : 0.f;
    }
    __syncthreads();
    for (int jj = 0; jj < 64; ++jj){
      int j = c0 + jj;
      float vs = -VMAXf + (j + 0.5f)*DVf;
      float wpj = (vs > 0.f ? vs : 0.f)*DVf;
      float wmj = (vs < 0.f ? vs : 0.f)*DVf;
      float av[4], bv[4], bm[4];
      #pragma unroll
      for (int k=0;k<4;k++){ av[k]=Vt[a0+k][jj+1]; bv[k]=Vt[b0+k][jj+1]; bm[k]=Vt[b0+k][jj]; }
      float lag = (j >= 1) ? 1.f : 0.f;
      #pragma unroll
      for (int ka=0;ka<4;ka++){
        #pragma unroll
        for (int kb=0;kb<4;kb++){
          float p = av[ka]*bv[kb];
          acc0[ka][kb] += p;
          accp[ka][kb] += p*wpj;
          accm[ka][kb] += p*wmj;
          acc1[ka][kb] += lag*av[ka]*bm[kb];
        }
      }
      if (tb == 0){
        float mv = fm*expf(-0.5f*Amax*vs*vs)*DVf;
        #pragma unroll
        for (int k=0;k<4;k++){
          vsv[k] += av[k];
          vvm[k] += av[k]*mv;
          vwv[k] += av[k]*wpj;
        }
      }
    }
    __syncthreads();
  }
  float* pb = part + (size_t)(sp*nbk+blk)*PS_V;
  #pragma unroll
  for (int ka=0;ka<4;ka++){
    #pragma unroll
    for (int kb=0;kb<4;kb++){
      int idx = (a0+ka)*64 + (b0+kb);
      pb[idx]        = acc0[ka][kb];
      pb[4096+idx]   = acc1[ka][kb];
      pb[8192+idx]   = accp[ka][kb];
      pb[12288+idx]  = accm[ka][kb];
    }
  }
  if (tb == 0){
    #pragma unroll
    for (int k=0;k<4;k++){
      pb[16384 + a0+k] = vsv[k];
      pb[16448 + a0+k] = vvm[k];
      pb[16512 + a0+k] = vwv[k];
    }
  }
}

// ---------------- X stats ----------------
__global__ __launch_bounds__(256) void k_xstatsf(const float* __restrict__ X0, const float* __restrict__ X1,
                                                 int pitch, const float* __restrict__ gsh, float* __restrict__ part){
  __shared__ float Xt[64][67];
  int sp = blockIdx.y;
  const float* X = sp ? X1 : X0;
  int blk = blockIdx.x;
  int nbk = gridDim.x;
  int chunk = NXC/nbk;
  int c0b = blk*chunk;
  int tid = threadIdx.x, ta = tid>>4, tb = tid&15, a0 = ta*4, b0 = tb*4;
  float accg[4][4]={{0}}, acch[4][4]={{0}};
  float axg[4]={0,0,0,0};
  for (int t0=0;t0<chunk;t0+=64){
    int c0 = c0b+t0;
    for (int i=tid;i<64*65;i+=256){
      int r=i/65, cc=i%65; int x=c0-1+cc;
      Xt[r][cc] = (x>=0 && x<NXC) ? X[(size_t)r*pitch + x] : 0.f;
    }
    __syncthreads();
    for (int jj=0;jj<64;jj++){
      int x = c0+jj;
      float av[4],bv[4],bm[4];
      #pragma unroll
      for (int k=0;k<4;k++){ av[k]=Xt[a0+k][jj+1]; bv[k]=Xt[b0+k][jj+1]; bm[k]=Xt[b0+k][jj]; }
      float lag = (x>=1)?1.f:0.f;
      #pragma unroll
      for (int ka=0;ka<4;ka++){
        #pragma unroll
        for (int kb=0;kb<4;kb++){
          accg[ka][kb] += av[ka]*bv[kb];
          acch[ka][kb] += lag*av[ka]*bm[kb];
        }
      }
      if (tb==0){
        float gw = gsh[x]*DXf;
        #pragma unroll
        for (int k=0;k<4;k++) axg[k] += av[k]*gw;
      }
    }
    __syncthreads();
  }
  float* pb = part + (size_t)(sp*nbk+blk)*PS_X;
  #pragma unroll
  for (int ka=0;ka<4;ka++){
    #pragma unroll
    for (int kb=0;kb<4;kb++){
      int idx = (a0+ka)*64 + (b0+kb);
      pb[idx] = accg[ka][kb];
      pb[4096+idx] = acch[ka][kb];
    }
  }
  if (tb==0){
    #pragma unroll
    for (int k=0;k<4;k++) pb[8192 + a0+k] = axg[k];
  }
}

// ---------------- E-weighted grams ----------------
__global__ __launch_bounds__(256) void k_eweightf(const float* __restrict__ X0, const float* __restrict__ X1,
                                                  int pitch, const float* __restrict__ E,
                                                  float fac0, float fac1, float* __restrict__ part){
  __shared__ float Xt[64][65];
  __shared__ float Ew[64];
  int sp = blockIdx.y;
  const float* X = sp ? X1 : X0;
  float fac = sp ? fac1 : fac0;
  int blk = blockIdx.x;
  int nbk = gridDim.x;
  int chunk = NXC/nbk;
  int c0b = blk*chunk;
  int tid = threadIdx.x, ta = tid>>4, tb = tid&15, a0 = ta*4, b0 = tb*4;
  float accp[4][4]={{0}}, accm[4][4]={{0}};
  for (int t0=0;t0<chunk;t0+=64){
    int c0 = c0b+t0;
    for (int i=tid;i<64*64;i+=256){
      int r=i>>6, cc=i&63;
      Xt[r][cc] = X[(size_t)r*pitch + c0+cc];
    }
    if (tid < 64) Ew[tid] = E[c0+tid]*fac;
    __syncthreads();
    for (int jj=0;jj<64;jj++){
      float w0 = Ew[jj];
      float wp = (w0>0.f?w0:0.f)*DXf, wm = (w0<0.f?w0:0.f)*DXf;
      float av[4],bv[4];
      #pragma unroll
      for (int k=0;k<4;k++){ av[k]=Xt[a0+k][jj]; bv[k]=Xt[b0+k][jj]; }
      #pragma unroll
      for (int ka=0;ka<4;ka++){
        #pragma unroll
        for (int kb=0;kb<4;kb++){
          float p = av[ka]*bv[kb];
          accp[ka][kb] += p*wp;
          accm[ka][kb] += p*wm;
        }
      }
    }
    __syncthreads();
  }
  float* pb = part + (size_t)(sp*nbk+blk)*PS_E;
  #pragma unroll
  for (int ka=0;ka<4;ka++){
    #pragma unroll
    for (int kb=0;kb<4;kb++){
      int idx = (a0+ka)*64 + (b0+kb);
      pb[idx] = accp[ka][kb];
      pb[4096+idx] = accm[ka][kb];
    }
  }
}

// ---------------- reductions ----------------
__global__ __launch_bounds__(256) void k_reduce32f(const float* __restrict__ part, int nb, int ps,
                                                   float* __restrict__ dst){
  int sp = blockIdx.y;
  int i = blockIdx.x*256 + threadIdx.x;
  if (i < ps){
    float s = 0.f;
    for (int b=0;b<nb;b++) s += part[(size_t)(sp*nb+b)*ps + i];
    dst[(size_t)sp*ps + i] = s;
  }
}

// reduce E-gram partials -> ED (for sprod) AND packed {Ep,Em} (for lstep)
__global__ __launch_bounds__(256) void k_reduceEpk(const float* __restrict__ part, int nb,
                                                   float* __restrict__ EDdst, float* __restrict__ EPMdst){
  int sp = blockIdx.y;
  int i = blockIdx.x*256 + threadIdx.x;
  if (i < 4096){
    float sp_ = 0.f, sm_ = 0.f;
    for (int b=0;b<nb;b++){
      const float* pb = part + (size_t)(sp*nb+b)*PS_E;
      sp_ += pb[i];
      sm_ += pb[4096+i];
    }
    float* ed = EDdst + (size_t)sp*PS_E;
    ed[i] = sp_; ed[4096+i] = sm_;
    float* ep = EPMdst + (size_t)sp*8192;
    ep[2*i] = sp_; ep[2*i+1] = sm_;
  }
}

// ---------------- prep kernels ----------------
__global__ __launch_bounds__(256) void k_prep1(
  const float* __restrict__ Ve, const float* __restrict__ Vi,
  const float* __restrict__ Se, const float* __restrict__ Si, const float* __restrict__ Xi,
  const float* __restrict__ VDe, const float* __restrict__ VDi,
  float* __restrict__ Vle, float* __restrict__ Vre, float* __restrict__ Vli, float* __restrict__ Vri,
  float* __restrict__ PKe, float* __restrict__ PKi,
  float* __restrict__ PLRe, float* __restrict__ PLRi,
  float* __restrict__ ae, float* __restrict__ ai, float* __restrict__ fluxg)
{
  int t = threadIdx.x;
  const float* g0e = VDe; const float* g1e = VDe+4096;
  const float* g0i = VDi; const float* g1i = VDi+4096;
  const float* sVe = VDe+16384; const float* sVi = VDi+16384;
  const float* wvi = VDi+16512;
  for (int i=t;i<4096;i+=256){
    int a=i>>6, b=i&63;
    int it = b*64+a;
    float v0a=Ve[(size_t)a*NVC], v0b=Ve[(size_t)b*NVC];
    float vea=Ve[(size_t)a*NVC+NVC-1], veb=Ve[(size_t)b*NVC+NVC-1];
    float vle = (g0e[i] - v0a*v0b) - g1e[i];
    float vre = g1e[it] - g0e[i] + vea*veb;
    Vle[i] = vle;
    Vre[i] = vre;
    PLRe[2*it]   = vle;
    PLRe[2*it+1] = vre;
    PKe[2*i]   = VDe[8192+i];
    PKe[2*i+1] = VDe[12288+i];
    float w0a=Vi[(size_t)a*NVC], w0b=Vi[(size_t)b*NVC];
    float wea=Vi[(size_t)a*NVC+NVC-1], web=Vi[(size_t)b*NVC+NVC-1];
    float vli = (g0i[i] - w0a*w0b) - g1i[i];
    float vri = g1i[it] - g0i[i] + wea*web;
    Vli[i] = vli;
    Vri[i] = vri;
    PLRi[2*it]   = vli;
    PLRi[2*it+1] = vri;
    PKi[2*i]   = VDi[8192+i];
    PKi[2*i+1] = VDi[12288+i];
  }
  __shared__ float red[64];
  if (t < 64){
    float s1=0.f,s2=0.f,tr=0.f;
    for (int q=0;q<64;q++){
      s1 += Se[t*64+q]*sVe[q];
      s2 += Si[t*64+q]*sVi[q];
      tr += Xi[(size_t)q*NXC + (NXC-1)]*Si[q*64+t];
    }
    ae[t]=s1; ai[t]=s2; red[t]=tr*wvi[t];
  }
  __syncthreads();
  if (t==0){ float s=0.f; for (int r=0;r<64;r++) s+=red[r]; fluxg[0]=s; }
}

__global__ __launch_bounds__(256) void k_prep2(const float* __restrict__ Sce, const float* __restrict__ Sci,
    const float* __restrict__ VDe, const float* __restrict__ VDi, const float* __restrict__ XiN,
    const float* __restrict__ XDe, const float* __restrict__ XDi,
    float* __restrict__ ae, float* __restrict__ ai,
    float* __restrict__ Xnge, float* __restrict__ Xngi, float* __restrict__ fluxg)
{
  const float* sVe = VDe+16384; const float* sVi = VDi+16384; const float* wvi = VDi+16512;
  __shared__ float red[64];
  int t=threadIdx.x;
  if (t<64){
    float s1=0.f,s2=0.f,tr=0.f;
    for (int q=0;q<64;q++){
      s1 += Sce[t*64+q]*sVe[q];
      s2 += Sci[t*64+q]*sVi[q];
      tr += XiN[(size_t)q*OUTWC + (NXC-1)]*Sci[q*64+t];
    }
    ae[t]=s1; ai[t]=s2; red[t]=tr*wvi[t];
  }
  __syncthreads();
  if (t==0){ float s=0.f; for(int r=0;r<64;r++) s+=red[r]; fluxg[1]=s; }
  __syncthreads();
  if (t<64){
    float y1=0.f,y2=0.f;
    for (int q=0;q<64;q++){
      y1 += XDe[t*64+q]*ae[q];
      y2 += XDi[t*64+q]*ai[q];
    }
    float f = fluxg[1];
    Xnge[t] = 1.0f *DXf*DVf*y1 + f*XDe[8192+t];
    Xngi[t] = 0.04f*DXf*DVf*y2 + f*XDi[8192+t];
  }
}

__global__ __launch_bounds__(256) void k_prep3(const float* __restrict__ S2e, const float* __restrict__ S2i,
    const float* __restrict__ VDe, const float* __restrict__ VDi, const float* __restrict__ XiN,
    const float* __restrict__ XDe, const float* __restrict__ XDi,
    float* __restrict__ G4e, float* __restrict__ G4i,
    float* __restrict__ ae, float* __restrict__ ai,
    float* __restrict__ Xnge, float* __restrict__ Xngi, float* __restrict__ fluxg)
{
  const float* sVe = VDe+16384; const float* sVi = VDi+16384; const float* wvi = VDi+16512;
  const float* Ge = XDe; const float* Gi = XDi;
  const float* XGe = XDe+8192; const float* XGi = XDi+8192;
  __shared__ float red[64];
  int t=threadIdx.x;
  for (int i=t;i<4096;i+=256){
    int it = (i&63)*64 + (i>>6);
    float4 ge; ge.x = XDe[i]; ge.y = XDe[4096+it]; ge.z = XDe[4096+i]; ge.w = 0.f;
    *reinterpret_cast<float4*>(&G4e[4*i]) = ge;
    float4 gi; gi.x = XDi[i]; gi.y = XDi[4096+it]; gi.z = XDi[4096+i]; gi.w = 0.f;
    *reinterpret_cast<float4*>(&G4i[4*i]) = gi;
  }
  if (t<64){
    float s1=0.f,s2=0.f,tr=0.f;
    for (int q=0;q<64;q++){
      s1 += S2e[t*64+q]*sVe[q];
      s2 += S2i[t*64+q]*sVi[q];
      tr += XiN[(size_t)q*OUTWC + (NXC-1)]*S2i[q*64+t];
    }
    ae[t]=s1; ai[t]=s2; red[t]=tr*wvi[t];
  }
  __syncthreads();
  if (t==0){ float s=0.f; for(int r=0;r<64;r++) s+=red[r]; fluxg[2]=s; }
  __syncthreads();
  if (t<64){
    float y1=0.f,y2=0.f;
    for (int q=0;q<64;q++){ y1 += Ge[t*64+q]*ae[q]; y2 += Gi[t*64+q]*ai[q]; }
    float f3 = fluxg[2];
    Xnge[t] = 1.0f *DXf*DVf*y1 + f3*XGe[t];
    Xngi[t] = 0.04f*DXf*DVf*y2 + f3*XGi[t];
  }
}

// ---------------- rho ----------------
__global__ __launch_bounds__(256) void k_rho(const float* __restrict__ Xe, int pe,
                                             const float* __restrict__ Xi, int pi,
                                             const float* __restrict__ ae, const float* __restrict__ ai,
                                             float* __restrict__ rho){
  int x = blockIdx.x*256 + threadIdx.x;
  float s = 0.f;
  for (int r=0;r<64;r++) s += ai[r]*Xi[(size_t)r*pi + x] - ae[r]*Xe[(size_t)r*pe + x];
  rho[x] = DVf*s;
}

// ---------------- poisson ----------------
__global__ __launch_bounds__(1024) void k_poisson(const float* __restrict__ rho, float* __restrict__ E){
  __shared__ float wsum[16];
  __shared__ float bsum[16];
  int t = threadIdx.x;
  int base = t*32;
  float loc[32];
  float run = 0.f;
  #pragma unroll
  for (int i=0;i<32;i++){ run += rho[base+i]; loc[i]=run; }
  float v = run;
  for (int off=1; off<64; off<<=1){
    float u = __shfl_up(v, off, 64);
    if ((t&63) >= off) v += u;
  }
  int wave = t>>6;
  if ((t&63)==63) wsum[wave] = v;
  __syncthreads();
  if (t==0){
    float a=0.f;
    for (int w0=0;w0<16;w0++){ float x=wsum[w0]; wsum[w0]=a; a+=x; }
  }
  __syncthreads();
  float offset = wsum[wave] + (v - run);
  float msum = 0.f;
  #pragma unroll
  for (int i=0;i<32;i++){ float e = DXf*(offset + loc[i]); loc[i]=e; msum += e; }
  float rs2 = msum;
  for (int off=32; off>0; off>>=1) rs2 += __shfl_down(rs2, off, 64);
  if ((t&63)==0) bsum[wave]=rs2;
  __syncthreads();
  if (t==0){ float a=0.f; for(int w0=0;w0<16;w0++) a+=bsum[w0]; bsum[0]=a; }
  __syncthreads();
  float mean = bsum[0]/(float)NXC;
  #pragma unroll
  for (int i=0;i<32;i++) E[base+i] = loc[i]-mean;
}

// ---------------- K step v9: 256 thr, 64-col tile, 16 cols/thread, packed loads ----------------
struct KArg { const float *X, *S, *VD, *PK, *PLR; float nu, fac; float* Kout; };
__global__ __launch_bounds__(256) void k_kstepf(KArg k0, KArg k1,
    const float* __restrict__ E, const float* __restrict__ gsh, const float* __restrict__ fluxg)
{
  KArg A = blockIdx.y ? k1 : k0;
  __shared__ float Sl[64*65];
  __shared__ __align__(16) float Xt[64*68];
  __shared__ __align__(16) float Kt[64*68];
  __shared__ float sVs[64], VMs[64];
  int x0 = blockIdx.x*64;
  int tid = threadIdx.x;
  for (int i=tid;i<4096;i+=256) Sl[(i>>6)*65+(i&63)] = A.S[i];
  for (int i=tid;i<64*68;i+=256){
    int r=i/68, cc=i%68; int x = x0-1+cc;
    Xt[i] = (cc<66 && x>=0 && x<NXC)? A.X[(size_t)r*NXC+x] : 0.f;
  }
  if (tid<64){ sVs[tid]=A.VD[16384+tid]; VMs[tid]=A.VD[16448+tid]; }
  __syncthreads();
  // phase 1: Kt[q][cc] = sum_p S[p][q]*X[p][cc]; float4 over cc (17 groups of 4)
  for (int u=tid; u<64*17; u+=256){
    int q=u/17, cc0=(u%17)*4;
    float ax=0.f, ay=0.f, az=0.f, aw=0.f;
    for (int p=0;p<64;p++){
      float s = Sl[p*65+q];
      float4 xv = *reinterpret_cast<const float4*>(&Xt[p*68+cc0]);
      ax += s*xv.x; ay += s*xv.y; az += s*xv.z; aw += s*xv.w;
    }
    float4 o; o.x=ax; o.y=ay; o.z=az; o.w=aw;
    *reinterpret_cast<float4*>(&Kt[q*68+cc0]) = o;
  }
  __syncthreads();
  // phase 3: 4 waves x 16 cols; lane = row r
  int r = tid & 63, w16 = (tid>>6)*16;
  float fo = fluxg[0];
  const float DTDX = DTf/DXf;
  const float* __restrict__ PK  = A.PK;
  const float* __restrict__ PLR = A.PLR;
  float acc[16], nacc[16], epv[16], emv[16];
  #pragma unroll
  for (int c=0;c<16;c++){
    int x = x0 + w16 + c;
    float Ex = A.fac*E[x];
    epv[c] = DTf*(Ex>0.f?Ex:0.f); emv[c] = DTf*(Ex<0.f?Ex:0.f);
    acc[c]=0.f; nacc[c]=0.f;
  }
  #pragma unroll 2
  for (int q=0;q<64;q++){
    int qi = (q<<6) + r;
    float2 pk = *reinterpret_cast<const float2*>(&PK[2*qi]);
    float2 pl = *reinterpret_cast<const float2*>(&PLR[2*qi]);
    float vp_ = DTDX*pk.x;
    float vm_ = DTDX*pk.y;
    float vl  = pl.x;
    float vr  = pl.y;
    float sq  = sVs[q];
    float w0 = vm_ - vp_;
    const float4 kA = *reinterpret_cast<const float4*>(&Kt[q*68 + w16]);
    const float4 kB = *reinterpret_cast<const float4*>(&Kt[q*68 + w16 + 4]);
    const float4 kC = *reinterpret_cast<const float4*>(&Kt[q*68 + w16 + 8]);
    const float4 kD = *reinterpret_cast<const float4*>(&Kt[q*68 + w16 + 12]);
    const float2 kE = *reinterpret_cast<const float2*>(&Kt[q*68 + w16 + 16]);
    float kseg[18] = {kA.x,kA.y,kA.z,kA.w,kB.x,kB.y,kB.z,kB.w,
                      kC.x,kC.y,kC.z,kC.w,kD.x,kD.y,kD.z,kD.w,kE.x,kE.y};
    #pragma unroll
    for (int c=0;c<16;c++){
      float kk0 = kseg[c+1];
      float t = w0 - (epv[c]*vl + emv[c]*vr);
      acc[c] += t*kk0 + vp_*kseg[c] - vm_*kseg[c+2];
      nacc[c] += sq*kk0;
    }
  }
  float vmr = VMs[r];
  #pragma unroll
  for (int c=0;c<16;c++){
    int x = x0 + w16 + c;
    float y = Kt[r*68 + w16 + c + 1]*(1.f - DTf*A.nu) + acc[c]
            + DTf*(nacc[c]*DVf*A.nu + fo*gsh[x])*vmr;
    A.Kout[(size_t)r*NXC + x] = y;
  }
}

// ---------------- L step v9: 256 thr, 64-col tile, 16 cols/thread, packed loads ----------------
struct LArg { const float *V, *S2, *G4, *EPM, *Xng; float nu, Amax; float* Lout; };
__global__ __launch_bounds__(256) void k_lstepf(LArg l0, LArg l1)
{
  LArg A = blockIdx.y ? l1 : l0;
  __shared__ float S2l[64*65];
  __shared__ __align__(16) float Vt[64*68];
  __shared__ __align__(16) float Lt[64*68];
  __shared__ float xngs[64];
  int v0 = blockIdx.x*64;
  int tid = threadIdx.x;
  for (int i=tid;i<4096;i+=256) S2l[(i>>6)*65+(i&63)] = A.S2[i];
  for (int i=tid;i<64*68;i+=256){
    int r=i/68, cc=i%68; int vv = v0-1+cc;
    Vt[i] = (cc<66 && vv>=0 && vv<NVC)? A.V[(size_t)r*NVC+vv] : 0.f;
  }
  if (tid<64) xngs[tid]=A.Xng[tid];
  __syncthreads();
  for (int u=tid; u<64*17; u+=256){
    int rr=u/17, cc0=(u%17)*4;
    float ax=0.f, ay=0.f, az=0.f, aw=0.f;
    for (int q=0;q<64;q++){
      float s = S2l[rr*65+q];
      float4 xv = *reinterpret_cast<const float4*>(&Vt[q*68+cc0]);
      ax += s*xv.x; ay += s*xv.y; az += s*xv.z; aw += s*xv.w;
    }
    float4 o; o.x=ax; o.y=ay; o.z=az; o.w=aw;
    *reinterpret_cast<float4*>(&Lt[rr*68+cc0]) = o;
  }
  __syncthreads();
  int r = tid & 63, w16 = (tid>>6)*16;
  const float DTDV = DTf/DVf;
  const float* __restrict__ G4  = A.G4;
  const float* __restrict__ EPM = A.EPM;
  float fm = sqrtf(A.Amax*INV2PI);
  float acc[16], vpc[16], vmc[16], mvv[16];
  #pragma unroll
  for (int c=0;c<16;c++){
    int vgl = v0 + w16 + c;
    float vs = -VMAXf + (vgl+0.5f)*DVf;
    vpc[c] = vs>0.f?vs:0.f; vmc[c] = vs<0.f?vs:0.f;
    mvv[c] = fm*expf(-0.5f*A.Amax*vs*vs);
    acc[c] = 0.f;
  }
  #pragma unroll 2
  for (int q=0;q<64;q++){
    int qi = (q<<6) + r;
    float4 g4 = *reinterpret_cast<const float4*>(&G4[4*qi]);
    float2 e2 = *reinterpret_cast<const float2*>(&EPM[2*qi]);
    float g  = g4.x;
    float h  = g4.y;
    float ht = g4.z;
    float ep = e2.x;
    float em = e2.y;
    float gh = DTf*(g-h), hg = DTf*(ht-g);
    float dep = DTDV*ep, dem = DTDV*em;
    float b0 = -DTf*A.nu*DXf*g - (dep - dem);
    const float4 lA = *reinterpret_cast<const float4*>(&Lt[q*68 + w16]);
    const float4 lB = *reinterpret_cast<const float4*>(&Lt[q*68 + w16 + 4]);
    const float4 lC = *reinterpret_cast<const float4*>(&Lt[q*68 + w16 + 8]);
    const float4 lD = *reinterpret_cast<const float4*>(&Lt[q*68 + w16 + 12]);
    const float2 lE = *reinterpret_cast<const float2*>(&Lt[q*68 + w16 + 16]);
    float lseg[18] = {lA.x,lA.y,lA.z,lA.w,lB.x,lB.y,lB.z,lB.w,
                      lC.x,lC.y,lC.z,lC.w,lD.x,lD.y,lD.z,lD.w,lE.x,lE.y};
    #pragma unroll
    for (int c=0;c<16;c++){
      float t = b0 - (vpc[c]*gh + vmc[c]*hg);
      acc[c] += t*lseg[c+1] + dep*lseg[c] - dem*lseg[c+2];
    }
  }
  float xr = xngs[r];
  #pragma unroll
  for (int c=0;c<16;c++){
    int vgl = v0 + w16 + c;
    float y = Lt[r*68 + w16 + c + 1] + acc[c] + DTf*xr*mvv[c];
    A.Lout[(size_t)r*NVC + vgl] = y;
  }
}

// ---------------- S step products ----------------
struct SPArg { const float *S, *XD, *ED, *Vl, *Vr, *VD; float nu; float* P; };
__global__ __launch_bounds__(256) void k_sprod(SPArg ea, SPArg ia){
  SPArg A = blockIdx.z ? ia : ea;
  int p  = blockIdx.y;
  int r0 = blockIdx.x*16;
  __shared__ float Sl[4096];
  __shared__ float Mb[16*65];
  __shared__ float M2[64*65];
  __shared__ float Tt[16*65];
  int tid = threadIdx.x;
  const float* G  = A.XD;
  const float* H  = A.XD + 4096;
  const float* Ep = A.ED;
  const float* Em = A.ED + 4096;
  for (int i=tid;i<4096;i+=256) Sl[i] = A.S[i];
  for (int i=tid;i<1024;i+=256){
    int rr=i>>6, c=i&63, r=r0+rr;
    float m;
    if      (p==0) m = G[r*64+c]-H[r*64+c];
    else if (p==1) m = H[c*64+r]-G[r*64+c];
    else if (p==2) m = Ep[r*64+c];
    else if (p==3) m = Em[r*64+c];
    else           m = G[r*64+c];
    Mb[rr*65+c]=m;
  }
  __syncthreads();
  int rr = tid>>4, b0 = (tid&15)*4;
  float acc[4]={0.f,0.f,0.f,0.f};
  for (int c=0;c<64;c++){
    float m = Mb[rr*65+c];
    #pragma unroll
    for (int k=0;k<4;k++) acc[k] += m*Sl[c*64+b0+k];
  }
  if (p==4){
    float s = A.nu*DXf;
    #pragma unroll
    for (int k=0;k<4;k++) A.P[(size_t)p*4096 + (r0+rr)*64 + b0+k] = s*acc[k];
    return;
  }
  #pragma unroll
  for (int k=0;k<4;k++) Tt[rr*65+b0+k]=acc[k];
  if (p<2){
    const float* src = (p==0)? A.VD+8192 : A.VD+12288;
    for (int i=tid;i<4096;i+=256){ int c=i>>6,b=i&63; M2[c*65+b]=src[i]; }
  } else {
    const float* src = (p==2)? A.Vl : A.Vr;
    for (int i=tid;i<4096;i+=256){ int b=i>>6,c=i&63; M2[c*65+b]=src[i]; }
  }
  __syncthreads();
  float acc2[4]={0.f,0.f,0.f,0.f};
  for (int c=0;c<64;c++){
    float t = Tt[rr*65+c];
    #pragma unroll
    for (int k=0;k<4;k++) acc2[k] += t*M2[c*65+b0+k];
  }
  #pragma unroll
  for (int k=0;k<4;k++) A.P[(size_t)p*4096 + (r0+rr)*64 + b0+k] = acc2[k];
}

// ---------------- S step combine ----------------
__global__ __launch_bounds__(256) void k_scomb(const float* __restrict__ Se, const float* __restrict__ Si,
    const float* __restrict__ P,
    const float* __restrict__ Xnge, const float* __restrict__ Xngi,
    const float* __restrict__ VDe, const float* __restrict__ VDi,
    float* __restrict__ S2e, float* __restrict__ S2i){
  int sp = blockIdx.y;
  int i = blockIdx.x*256 + threadIdx.x;
  const float* S   = sp ? Si : Se;
  const float* Pb  = P + (size_t)sp*5*4096;
  const float* xng = sp ? Xngi : Xnge;
  const float* VMv = (sp ? VDi : VDe) + 16448;
  float* S2 = sp ? S2i : S2e;
  int a=i>>6, b=i&63;
  float s = ((Pb[i] + Pb[4096+i]) + (Pb[8192+i] + Pb[12288+i])) + Pb[16384+i] - xng[a]*VMv[b];
  S2[i] = S[i] + DTf*s;
}

// ---------------- Gram: all-fp32, 128 blocks/species ----------------
__global__ __launch_bounds__(256) void k_gramf(const float* __restrict__ A0, const float* __restrict__ A1,
                                               int n, float* __restrict__ part){
  __shared__ float At[64][65];
  int sp = blockIdx.y;
  const float* A = sp ? A1 : A0;
  int blk = blockIdx.x, nb = gridDim.x;
  int chunk = n/nb;
  int c0b = blk*chunk;
  int tid=threadIdx.x, ta=tid>>4, tb=tid&15, a0=ta*4, b0=tb*4;
  float acc[4][4]={{0}};
  for (int t0=0;t0<chunk;t0+=64){
    int c0=c0b+t0;
    for (int i=tid;i<64*64;i+=256){ int r=i>>6, cc=i&63; At[r][cc]=A[(size_t)r*n + c0+cc]; }
    __syncthreads();
    for (int cc=0;cc<64;cc++){
      float av[4],bv[4];
      #pragma unroll
      for(int k=0;k<4;k++){ av[k]=At[a0+k][cc]; bv[k]=At[b0+k][cc]; }
      #pragma unroll
      for(int ka=0;ka<4;ka++){
        #pragma unroll
        for(int kb=0;kb<4;kb++) acc[ka][kb] += av[ka]*bv[kb];
      }
    }
    __syncthreads();
  }
  float* pb = part + (size_t)(sp*nb+blk)*4096;
  #pragma unroll
  for(int ka=0;ka<4;ka++){
    #pragma unroll
    for(int kb=0;kb<4;kb++) pb[(a0+ka)*64 + b0+kb] = acc[ka][kb];
  }
}

// ---------------- blocked fp32 Cholesky ----------------
__device__ void chol_blk32(float* __restrict__ M, int tid){
  for (int p=0;p<8;p++){
    const int b=8*p;
    if (tid<64){
      float st[8];
      #pragma unroll
      for (int j=0;j<8;j++) st[j] = M[(b+j)*65 + tid];
      #pragma unroll
      for (int kk=0;kk<8;kk++){
        float q[8];
        #pragma unroll
        for (int j=0;j<8;j++) q[j] = __shfl(st[kk], b+j, 64);
        float d = q[kk];
        float rinv = (d > 0.f) ? 1.f/d : 0.f;
        float sk = st[kk];
        #pragma unroll
        for (int j=0;j<8;j++) if (j>kk) st[j] -= q[j]*sk*rinv;
        st[kk] = sk * ((d > 0.f)? rsqrtf(d) : 0.f);
      }
      #pragma unroll
      for (int j=0;j<8;j++) M[(b+j)*65 + tid] = st[j];
    }
    __syncthreads();
    if (b+8 < 64){
      for (int i=(b+8)*64 + tid; i<4096; i+=512){
        int r=i>>6, c=i&63;
        if (c>=r){
          float s=0.f;
          #pragma unroll
          for (int j=0;j<8;j++) s += M[(b+j)*65+r]*M[(b+j)*65+c];
          M[r*65+c] -= s;
        }
      }
    }
    __syncthreads();
  }
}

// ---------------- fused QR: chol + Lw-inverse + block-parallel sign recursion ----------------
struct QArgs {
  const float* Gd; const float* A; int n;
  float scaleS, invQ;
  float* SolveM; float* Sout; int outPitch; int mode;
};
__global__ __launch_bounds__(512) void k_qr(QArgs q0, QArgs q1){
  QArgs Q = (blockIdx.x==0)? q0 : q1;
  __shared__ float Lg[64*65];
  __shared__ float Lw[64*65];
  __shared__ float T[64*65];
  __shared__ float TmpI[448];
  __shared__ float Dv[64];
  int tid = threadIdx.x;
  for (int i=tid;i<4096;i+=512) Lg[(i>>6)*65 + (i&63)] = Q.Gd[i];
  for (int i=tid;i<4096;i+=512){ int c=i>>6, r=i&63; T[r*65+c] = Q.A[(size_t)c*Q.n + r]; }
  __syncthreads();
  chol_blk32(Lg, tid);
  if (tid<64){
    int p=tid>>3, cc=tid&7, b=8*p;
    float wcol[8];
    #pragma unroll
    for (int r=7;r>=0;r--){
      float s = (r==cc)? 1.f : 0.f;
      #pragma unroll
      for (int j=0;j<8;j++) if (j>r) s -= Lg[(b+r)*65 + (b+j)]*wcol[j];
      float dg = Lg[(b+r)*65 + (b+r)];
      wcol[r] = (r<=cc && dg!=0.f)? s/dg : 0.f;
    }
    #pragma unroll
    for (int r=0;r<8;r++) Lw[(b+r)*65 + (b+cc)] = wcol[r];
  }
  __syncthreads();
  for (int d=1; d<8; d++){
    int nb2 = 8-d;
    if (tid < nb2*64){
      int bb=tid>>6, rc=tid&63, r=rc>>3, c=rc&7;
      int p=bb, qb=p+d;
      float s=0.f;
      for (int m=p+1;m<=qb;m++){
        #pragma unroll
        for (int jj=0;jj<8;jj++)
          s += Lg[(8*p+r)*65 + 8*m+jj]*Lw[(8*m+jj)*65 + 8*qb+c];
      }
      TmpI[tid]=s;
    }
    __syncthreads();
    if (tid < nb2*64){
      int bb=tid>>6, rc=tid&63, r=rc>>3, c=rc&7;
      int p=bb, qb=p+d;
      float s=0.f;
      #pragma unroll
      for (int rr=0;rr<8;rr++)
        s += Lw[(8*p+r)*65 + 8*p+rr]*TmpI[(bb<<6)+(rr<<3)+c];
      Lw[(8*p+r)*65 + 8*qb+c] = -s;
    }
    __syncthreads();
  }
  {
    int g = tid>>6, c = tid&63;
    int rbase = g*8;
    for (int k=0;k<64;k++){
      if (tid==k){
        float alpha = T[k*65+k];
        float Ckk = Lg[k*65+k];
        float beta = (alpha>=0.f)? -Ckk : Ckk;
        Dv[k] = (beta>=0.f)? 1.f : -1.f;
      }
      if (rbase+7 > k){
        float alpha = T[k*65+k];
        float Ckk = Lg[k*65+k];
        float beta = (alpha>=0.f)? -Ckk : Ckk;
        float vvh = Ckk*Ckk - alpha*beta;
        float ivv = (vvh>0.f)? __builtin_amdgcn_rcpf(vvh) : 0.f;
        float f = (Lg[k*65+c]*Ckk - beta*T[k*65+c])*ivv;
        if (c > k){
          #pragma unroll
          for (int j=0;j<8;j++){
            int r = rbase+j;
            if (r > k) T[r*65+c] -= f*T[r*65+k];
          }
        }
      }
      __syncthreads();
    }
  }
  for (int i=tid;i<4096;i+=512){
    int r=i>>6, q2=i&63;
    Q.SolveM[i] = (q2<=r)? (Dv[r]*Lw[q2*65+r]*Q.invQ) : 0.f;
    if (Q.mode==0){
      Q.Sout[i] = (q2>=r)? (Dv[r]*Lg[r*65+q2]*Q.scaleS) : 0.f;
    } else {
      Q.Sout[(size_t)r*Q.outPitch + q2] = (r>=q2)? (Dv[q2]*Lg[q2*65+r]*Q.scaleS) : 0.f;
    }
  }
}

// ---------------- Q formation ----------------
__global__ __launch_bounds__(256) void k_qformf(const float* __restrict__ A0, const float* __restrict__ A1,
    int n, const float* __restrict__ M0, const float* __restrict__ M1,
    float* __restrict__ O0, float* __restrict__ O1, int pitch)
{
  int sp = blockIdx.y >> 2;
  const float* A = sp ? A1 : A0;
  const float* M = sp ? M1 : M0;
  float* Out = sp ? O1 : O0;
  int x = blockIdx.x*256 + threadIdx.x;
  int r0 = (blockIdx.y & 3)*16;
  float acc[16];
  #pragma unroll
  for (int rr=0;rr<16;rr++) acc[rr]=0.f;
  for (int q=0;q<64;q++){
    float aq = A[(size_t)q*n + x];
    #pragma unroll
    for (int rr=0;rr<16;rr++) acc[rr] += M[(r0+rr)*64 + q]*aq;
  }
  #pragma unroll
  for (int rr=0;rr<16;rr++) Out[(size_t)(r0+rr)*pitch + x] = acc[rr];
}

// ======================= host =======================
extern "C" void kernel_launch(void* const* d_in, const int* in_sizes, int n_in,
                              void* d_out, int out_size, void* d_ws, size_t ws_size,
                              hipStream_t stream)
{
  (void)in_sizes; (void)n_in; (void)out_size; (void)ws_size;
  const float* Xe = (const float*)d_in[0];
  const float* Se = (const float*)d_in[1];
  const float* Ve = (const float*)d_in[2];
  const float* Xi = (const float*)d_in[3];
  const float* Si = (const float*)d_in[4];
  const float* Vi = (const float*)d_in[5];
  float* out = (float*)d_out;
  float* w = (float*)d_ws;

  size_t o = 0;
  auto alloc = [&](size_t nn){ size_t r=o; o += (nn+63)&~(size_t)63; return r; };
  size_t F_VD = alloc(2*PS_V);
  size_t F_XD = alloc(2*PS_X);
  size_t F_ED = alloc(2*PS_E);
  size_t F_VL_E = alloc(4096), F_VR_E = alloc(4096), F_VL_I = alloc(4096), F_VR_I = alloc(4096);
  size_t F_PK_E = alloc(8192), F_PK_I = alloc(8192);
  size_t F_PLR_E = alloc(8192), F_PLR_I = alloc(8192);
  size_t F_G4_E = alloc(16384), F_G4_I = alloc(16384);
  size_t F_EPM = alloc(2*8192);
  size_t F_SC_E = alloc(4096), F_SC_I = alloc(4096), F_S2_E = alloc(4096), F_S2_I = alloc(4096);
  size_t F_SOLVE_E = alloc(4096), F_SOLVE_I = alloc(4096);
  size_t F_AE = alloc(64), F_AI = alloc(64), F_XNGE = alloc(64), F_XNGI = alloc(64);
  size_t F_FLUX = alloc(64);
  size_t F_GSH = alloc(NXC);
  size_t F_RHO = alloc(NXC);
  size_t F_E   = alloc(NXC);
  size_t F_KE = alloc((size_t)64*NXC);
  size_t F_KI = alloc((size_t)64*NXC);
  size_t F_LE = F_KE;
  size_t F_LI = F_KI;
  size_t F_PART = alloc(1060864);
  size_t F_GQR = alloc(16384);
  float* Gqr = w + F_GQR;
  float* part = w + F_PART;
  float* vpart = w + F_KE;
  float* xpart = w + F_KE;
  float* epart = w + F_KE;
  float* Pbuf  = w + F_KE;
  const float* VDe = w + F_VD;
  const float* VDi = w + F_VD + PS_V;
  const float* XDe = w + F_XD;
  const float* XDi = w + F_XD + PS_X;
  const float* EDe = w + F_ED;
  const float* EDi = w + F_ED + PS_E;

  float sqDX = sqrtf(DXf), isqDX = 1.f/sqrtf(DXf);
  float sqDV = sqrtf(DVf), isqDV = 1.f/sqrtf(DVf);
  const float NUE = 1.0f, NUI = 0.04f;
  const float FACE = -1.0f, FACI = 1.0f/1836.0f;

  // --- V-derived stats ---
  k_vstatsf<<<dim3(128,2),256,0,stream>>>(Ve, Vi, vpart);
  k_reduce32f<<<dim3((PS_V+255)/256,2),256,0,stream>>>(vpart, 128, PS_V, w+F_VD);
  k_gshape<<<1,1024,0,stream>>>(w+F_GSH);
  k_prep1<<<1,256,0,stream>>>(Ve, Vi, Se, Si, Xi, VDe, VDi,
                              w+F_VL_E, w+F_VR_E, w+F_VL_I, w+F_VR_I,
                              w+F_PK_E, w+F_PK_I, w+F_PLR_E, w+F_PLR_I,
                              w+F_AE, w+F_AI, w+F_FLUX);
  // --- K step ---
  k_rho<<<NXC/256,256,0,stream>>>(Xe, NXC, Xi, NXC, w+F_AE, w+F_AI, w+F_RHO);
  k_poisson<<<1,1024,0,stream>>>(w+F_RHO, w+F_E);
  KArg ke{Xe, Se, VDe, w+F_PK_E, w+F_PLR_E, NUE, FACE, w+F_KE};
  KArg ki{Xi, Si, VDi, w+F_PK_I, w+F_PLR_I, NUI, FACI, w+F_KI};
  k_kstepf<<<dim3(NXC/64,2),256,0,stream>>>(ke, ki, w+F_E, w+F_GSH, w+F_FLUX);
  // --- QR of K^T ---
  k_gramf<<<dim3(128,2),256,0,stream>>>(w+F_KE, w+F_KI, NXC, part);
  k_reduce32f<<<dim3(16,2),256,0,stream>>>(part, 128, 4096, Gqr);
  {
    QArgs qe{Gqr,        w+F_KE, NXC, sqDX, isqDX, w+F_SOLVE_E, w+F_SC_E, 0, 0};
    QArgs qi{Gqr+4096,   w+F_KI, NXC, sqDX, isqDX, w+F_SOLVE_I, w+F_SC_I, 0, 0};
    k_qr<<<2,512,0,stream>>>(qe, qi);
  }
  k_qformf<<<dim3(NXC/256,8),256,0,stream>>>(w+F_KE, w+F_KI, NXC, w+F_SOLVE_E, w+F_SOLVE_I,
                                             out, out + (size_t)64*OUTWC, OUTWC);
  // --- X stats on new X ---
  k_xstatsf<<<dim3(128,2),256,0,stream>>>(out, out + (size_t)64*OUTWC, OUTWC, w+F_GSH, xpart);
  k_reduce32f<<<dim3((PS_X+255)/256,2),256,0,stream>>>(xpart, 128, PS_X, w+F_XD);
  // --- S step ---
  k_prep2<<<1,256,0,stream>>>(w+F_SC_E, w+F_SC_I, VDe, VDi, out + (size_t)64*OUTWC,
                              XDe, XDi,
                              w+F_AE, w+F_AI, w+F_XNGE, w+F_XNGI, w+F_FLUX);
  k_rho<<<NXC/256,256,0,stream>>>(out, OUTWC, out + (size_t)64*OUTWC, OUTWC, w+F_AE, w+F_AI, w+F_RHO);
  k_poisson<<<1,1024,0,stream>>>(w+F_RHO, w+F_E);
  k_eweightf<<<dim3(128,2),256,0,stream>>>(out, out + (size_t)64*OUTWC, OUTWC, w+F_E, FACE, FACI, epart);
  k_reduce32f<<<dim3((PS_E+255)/256,2),256,0,stream>>>(epart, 128, PS_E, w+F_ED);
  {
    SPArg spe{w+F_SC_E, XDe, EDe, w+F_VL_E, w+F_VR_E, VDe, NUE, Pbuf};
    SPArg spi{w+F_SC_I, XDi, EDi, w+F_VL_I, w+F_VR_I, VDi, NUI, Pbuf + 5*4096};
    k_sprod<<<dim3(4,5,2),256,0,stream>>>(spe, spi);
  }
  k_scomb<<<dim3(16,2),256,0,stream>>>(w+F_SC_E, w+F_SC_I, Pbuf, w+F_XNGE, w+F_XNGI,
                                       VDe, VDi, w+F_S2_E, w+F_S2_I);
  // --- L step ---
  k_prep3<<<1,256,0,stream>>>(w+F_S2_E, w+F_S2_I, VDe, VDi, out + (size_t)64*OUTWC,
                              XDe, XDi, w+F_G4_E, w+F_G4_I,
                              w+F_AE, w+F_AI, w+F_XNGE, w+F_XNGI, w+F_FLUX);
  k_rho<<<NXC/256,256,0,stream>>>(out, OUTWC, out + (size_t)64*OUTWC, OUTWC, w+F_AE, w+F_AI, w+F_RHO);
  k_poisson<<<1,1024,0,stream>>>(w+F_RHO, w+F_E);
  k_eweightf<<<dim3(128,2),256,0,stream>>>(out, out + (size_t)64*OUTWC, OUTWC, w+F_E, FACE, FACI, epart);
  k_reduceEpk<<<dim3(16,2),256,0,stream>>>(epart, 128, w+F_ED, w+F_EPM);
  LArg le{Ve, w+F_S2_E, w+F_G4_E, w+F_EPM,        w+F_XNGE, NUE, 1.0f,    w+F_LE};
  LArg li{Vi, w+F_S2_I, w+F_G4_I, w+F_EPM + 8192, w+F_XNGI, NUI, 1836.0f, w+F_LI};
  k_lstepf<<<dim3(NVC/64,2),256,0,stream>>>(le, li);
  // --- QR of L^T ---
  k_gramf<<<dim3(128,2),256,0,stream>>>(w+F_LE, w+F_LI, NVC, part);
  k_reduce32f<<<dim3(16,2),256,0,stream>>>(part, 128, 4096, Gqr);
  {
    QArgs qe{Gqr,      w+F_LE, NVC, sqDV, isqDV, w+F_SOLVE_E, out + NXC,                        OUTWC, 1};
    QArgs qi{Gqr+4096, w+F_LI, NVC, sqDV, isqDV, w+F_SOLVE_I, out + (size_t)64*OUTWC + NXC,     OUTWC, 1};
    k_qr<<<2,512,0,stream>>>(qe, qi);
  }
  k_qformf<<<dim3(NVC/256,8),256,0,stream>>>(w+F_LE, w+F_LI, NVC, w+F_SOLVE_E, w+F_SOLVE_I,
                                             out + NXC + 64, out + (size_t)64*OUTWC + NXC + 64, OUTWC);
}

// Round 13
// 876.700 us; speedup vs baseline: 1.0734x; 1.0734x over previous
//
#include <hip/hip_runtime.h>
#include <math.h>

#define NXC 32768
#define NVC 16384
#define OUTWC (NXC + 64 + NVC)

static constexpr float DXf   = 1.0f/32768.0f;
static constexpr float DVf   = 16.0f/16384.0f;
static constexpr float DTf   = 1e-3f;
static constexpr float VMAXf = 8.0f;
static constexpr float INV2PI= 0.15915494309189535f;

#define PS_V 16576
#define PS_X 8256
#define PS_E 8192

// ---------------- gshape ----------------
__global__ __launch_bounds__(1024) void k_gshape(float* __restrict__ g){
  __shared__ float red[1024];
  int t = threadIdx.x;
  float s = 0.f;
  for (int i = t; i < NXC; i += 1024){
    float x = (i + 0.5f)*DXf - 0.5f;
    float xx = x*10.0f;
    float gv = expf(-0.5f*xx*xx);
    g[i] = gv; s += gv;
  }
  red[t] = s; __syncthreads();
  for (int o = 512; o > 0; o >>= 1){ if (t < o) red[t] += red[t+o]; __syncthreads(); }
  float norm = 1.0f/(red[0]*DXf);
  for (int i = t; i < NXC; i += 1024) g[i] *= norm;
}

// ---------------- V stats ----------------
__global__ __launch_bounds__(256) void k_vstatsf(const float* __restrict__ V0, const float* __restrict__ V1,
                                                 float* __restrict__ part){
  __shared__ float Vt[64][67];
  int sp = blockIdx.y;
  const float* V = sp ? V1 : V0;
  float Amax = sp ? 1836.0f : 1.0f;
  int blk = blockIdx.x;
  int nbk = gridDim.x;
  int chunk = NVC/nbk;
  int c0b = blk*chunk;
  int tid = threadIdx.x;
  int ta = tid >> 4, tb = tid & 15;
  int a0 = ta*4, b0 = tb*4;
  float acc0[4][4]={{0}}, acc1[4][4]={{0}}, accp[4][4]={{0}}, accm[4][4]={{0}};
  float vsv[4]={0,0,0,0}, vvm[4]={0,0,0,0}, vwv[4]={0,0,0,0};
  float fm = sqrtf(Amax*INV2PI);
  for (int t0 = 0; t0 < chunk; t0 += 64){
    int c0 = c0b + t0;
    for (int i = tid; i < 64*65; i += 256){
      int r = i/65, cc = i%65;
      int c = c0 - 1 + cc;
      Vt[r][cc] = (c >= 0 && c < NVC) ? V[(size_t)r*NVC + c] : 0.f;
    }
    __syncthreads();
    for (int jj = 0; jj < 64; ++jj){
      int j = c0 + jj;
      float vs = -VMAXf + (j + 0.5f)*DVf;
      float wpj = (vs > 0.f ? vs : 0.f)*DVf;
      float wmj = (vs < 0.f ? vs : 0.f)*DVf;
      float av[4], bv[4], bm[4];
      #pragma unroll
      for (int k=0;k<4;k++){ av[k]=Vt[a0+k][jj+1]; bv[k]=Vt[b0+k][jj+1]; bm[k]=Vt[b0+k][jj]; }
      float lag = (j >= 1) ? 1.f : 0.f;
      #pragma unroll
      for (int ka=0;ka<4;ka++){
        #pragma unroll
        for (int kb=0;kb<4;kb++){
          float p = av[ka]*bv[kb];
          acc0[ka][kb] += p;
          accp[ka][kb] += p*wpj;
          accm[ka][kb] += p*wmj;
          acc1[ka][kb] += lag*av[ka]*bm[kb];
        }
      }
      if (tb == 0){
        float mv = fm*expf(-0.5f*Amax*vs*vs)*DVf;
        #pragma unroll
        for (int k=0;k<4;k++){
          vsv[k] += av[k];
          vvm[k] += av[k]*mv;
          vwv[k] += av[k]*wpj;
        }
      }
    }
    __syncthreads();
  }
  float* pb = part + (size_t)(sp*nbk+blk)*PS_V;
  #pragma unroll
  for (int ka=0;ka<4;ka++){
    #pragma unroll
    for (int kb=0;kb<4;kb++){
      int idx = (a0+ka)*64 + (b0+kb);
      pb[idx]        = acc0[ka][kb];
      pb[4096+idx]   = acc1[ka][kb];
      pb[8192+idx]   = accp[ka][kb];
      pb[12288+idx]  = accm[ka][kb];
    }
  }
  if (tb == 0){
    #pragma unroll
    for (int k=0;k<4;k++){
      pb[16384 + a0+k] = vsv[k];
      pb[16448 + a0+k] = vvm[k];
      pb[16512 + a0+k] = vwv[k];
    }
  }
}

// ---------------- X stats ----------------
__global__ __launch_bounds__(256) void k_xstatsf(const float* __restrict__ X0, const float* __restrict__ X1,
                                                 int pitch, const float* __restrict__ gsh, float* __restrict__ part){
  __shared__ float Xt[64][67];
  int sp = blockIdx.y;
  const float* X = sp ? X1 : X0;
  int blk = blockIdx.x;
  int nbk = gridDim.x;
  int chunk = NXC/nbk;
  int c0b = blk*chunk;
  int tid = threadIdx.x, ta = tid>>4, tb = tid&15, a0 = ta*4, b0 = tb*4;
  float accg[4][4]={{0}}, acch[4][4]={{0}};
  float axg[4]={0,0,0,0};
  for (int t0=0;t0<chunk;t0+=64){
    int c0 = c0b+t0;
    for (int i=tid;i<64*65;i+=256){
      int r=i/65, cc=i%65; int x=c0-1+cc;
      Xt[r][cc] = (x>=0 && x<NXC) ? X[(size_t)r*pitch + x] : 0.f;
    }
    __syncthreads();
    for (int jj=0;jj<64;jj++){
      int x = c0+jj;
      float av[4],bv[4],bm[4];
      #pragma unroll
      for (int k=0;k<4;k++){ av[k]=Xt[a0+k][jj+1]; bv[k]=Xt[b0+k][jj+1]; bm[k]=Xt[b0+k][jj]; }
      float lag = (x>=1)?1.f:0.f;
      #pragma unroll
      for (int ka=0;ka<4;ka++){
        #pragma unroll
        for (int kb=0;kb<4;kb++){
          accg[ka][kb] += av[ka]*bv[kb];
          acch[ka][kb] += lag*av[ka]*bm[kb];
        }
      }
      if (tb==0){
        float gw = gsh[x]*DXf;
        #pragma unroll
        for (int k=0;k<4;k++) axg[k] += av[k]*gw;
      }
    }
    __syncthreads();
  }
  float* pb = part + (size_t)(sp*nbk+blk)*PS_X;
  #pragma unroll
  for (int ka=0;ka<4;ka++){
    #pragma unroll
    for (int kb=0;kb<4;kb++){
      int idx = (a0+ka)*64 + (b0+kb);
      pb[idx] = accg[ka][kb];
      pb[4096+idx] = acch[ka][kb];
    }
  }
  if (tb==0){
    #pragma unroll
    for (int k=0;k<4;k++) pb[8192 + a0+k] = axg[k];
  }
}

// ---------------- E-weighted grams ----------------
__global__ __launch_bounds__(256) void k_eweightf(const float* __restrict__ X0, const float* __restrict__ X1,
                                                  int pitch, const float* __restrict__ E,
                                                  float fac0, float fac1, float* __restrict__ part){
  __shared__ float Xt[64][65];
  __shared__ float Ew[64];
  int sp = blockIdx.y;
  const float* X = sp ? X1 : X0;
  float fac = sp ? fac1 : fac0;
  int blk = blockIdx.x;
  int nbk = gridDim.x;
  int chunk = NXC/nbk;
  int c0b = blk*chunk;
  int tid = threadIdx.x, ta = tid>>4, tb = tid&15, a0 = ta*4, b0 = tb*4;
  float accp[4][4]={{0}}, accm[4][4]={{0}};
  for (int t0=0;t0<chunk;t0+=64){
    int c0 = c0b+t0;
    for (int i=tid;i<64*64;i+=256){
      int r=i>>6, cc=i&63;
      Xt[r][cc] = X[(size_t)r*pitch + c0+cc];
    }
    if (tid < 64) Ew[tid] = E[c0+tid]*fac;
    __syncthreads();
    for (int jj=0;jj<64;jj++){
      float w0 = Ew[jj];
      float wp = (w0>0.f?w0:0.f)*DXf, wm = (w0<0.f?w0:0.f)*DXf;
      float av[4],bv[4];
      #pragma unroll
      for (int k=0;k<4;k++){ av[k]=Xt[a0+k][jj]; bv[k]=Xt[b0+k][jj]; }
      #pragma unroll
      for (int ka=0;ka<4;ka++){
        #pragma unroll
        for (int kb=0;kb<4;kb++){
          float p = av[ka]*bv[kb];
          accp[ka][kb] += p*wp;
          accm[ka][kb] += p*wm;
        }
      }
    }
    __syncthreads();
  }
  float* pb = part + (size_t)(sp*nbk+blk)*PS_E;
  #pragma unroll
  for (int ka=0;ka<4;ka++){
    #pragma unroll
    for (int kb=0;kb<4;kb++){
      int idx = (a0+ka)*64 + (b0+kb);
      pb[idx] = accp[ka][kb];
      pb[4096+idx] = accm[ka][kb];
    }
  }
}

// ---------------- reductions ----------------
__global__ __launch_bounds__(256) void k_reduce32f(const float* __restrict__ part, int nb, int ps,
                                                   float* __restrict__ dst){
  int sp = blockIdx.y;
  int i = blockIdx.x*256 + threadIdx.x;
  if (i < ps){
    float s = 0.f;
    for (int b=0;b<nb;b++) s += part[(size_t)(sp*nb+b)*ps + i];
    dst[(size_t)sp*ps + i] = s;
  }
}

// ---------------- prep kernels ----------------
__global__ __launch_bounds__(256) void k_prep1(
  const float* __restrict__ Ve, const float* __restrict__ Vi,
  const float* __restrict__ Se, const float* __restrict__ Si, const float* __restrict__ Xi,
  const float* __restrict__ VDe, const float* __restrict__ VDi,
  float* __restrict__ Vle, float* __restrict__ Vre, float* __restrict__ Vli, float* __restrict__ Vri,
  float* __restrict__ ae, float* __restrict__ ai, float* __restrict__ fluxg)
{
  int t = threadIdx.x;
  const float* g0e = VDe; const float* g1e = VDe+4096;
  const float* g0i = VDi; const float* g1i = VDi+4096;
  const float* sVe = VDe+16384; const float* sVi = VDi+16384;
  const float* wvi = VDi+16512;
  for (int i=t;i<4096;i+=256){
    int a=i>>6, b=i&63;
    int it = b*64+a;
    float v0a=Ve[(size_t)a*NVC], v0b=Ve[(size_t)b*NVC];
    float vea=Ve[(size_t)a*NVC+NVC-1], veb=Ve[(size_t)b*NVC+NVC-1];
    Vle[i] = (g0e[i] - v0a*v0b) - g1e[i];
    Vre[i] = g1e[it] - g0e[i] + vea*veb;
    float w0a=Vi[(size_t)a*NVC], w0b=Vi[(size_t)b*NVC];
    float wea=Vi[(size_t)a*NVC+NVC-1], web=Vi[(size_t)b*NVC+NVC-1];
    Vli[i] = (g0i[i] - w0a*w0b) - g1i[i];
    Vri[i] = g1i[it] - g0i[i] + wea*web;
  }
  __shared__ float red[64];
  if (t < 64){
    float s1=0.f,s2=0.f,tr=0.f;
    for (int q=0;q<64;q++){
      s1 += Se[t*64+q]*sVe[q];
      s2 += Si[t*64+q]*sVi[q];
      tr += Xi[(size_t)q*NXC + (NXC-1)]*Si[q*64+t];
    }
    ae[t]=s1; ai[t]=s2; red[t]=tr*wvi[t];
  }
  __syncthreads();
  if (t==0){ float s=0.f; for (int r=0;r<64;r++) s+=red[r]; fluxg[0]=s; }
}

__global__ __launch_bounds__(256) void k_prep2(const float* __restrict__ Sce, const float* __restrict__ Sci,
    const float* __restrict__ VDe, const float* __restrict__ VDi, const float* __restrict__ XiN,
    const float* __restrict__ XDe, const float* __restrict__ XDi,
    float* __restrict__ ae, float* __restrict__ ai,
    float* __restrict__ Xnge, float* __restrict__ Xngi, float* __restrict__ fluxg)
{
  const float* sVe = VDe+16384; const float* sVi = VDi+16384; const float* wvi = VDi+16512;
  __shared__ float red[64];
  int t=threadIdx.x;
  if (t<64){
    float s1=0.f,s2=0.f,tr=0.f;
    for (int q=0;q<64;q++){
      s1 += Sce[t*64+q]*sVe[q];
      s2 += Sci[t*64+q]*sVi[q];
      tr += XiN[(size_t)q*OUTWC + (NXC-1)]*Sci[q*64+t];
    }
    ae[t]=s1; ai[t]=s2; red[t]=tr*wvi[t];
  }
  __syncthreads();
  if (t==0){ float s=0.f; for(int r=0;r<64;r++) s+=red[r]; fluxg[1]=s; }
  __syncthreads();
  if (t<64){
    float y1=0.f,y2=0.f;
    for (int q=0;q<64;q++){
      y1 += XDe[t*64+q]*ae[q];
      y2 += XDi[t*64+q]*ai[q];
    }
    float f = fluxg[1];
    Xnge[t] = 1.0f *DXf*DVf*y1 + f*XDe[8192+t];
    Xngi[t] = 0.04f*DXf*DVf*y2 + f*XDi[8192+t];
  }
}

__global__ __launch_bounds__(256) void k_prep3(const float* __restrict__ S2e, const float* __restrict__ S2i,
    const float* __restrict__ VDe, const float* __restrict__ VDi, const float* __restrict__ XiN,
    const float* __restrict__ XDe, const float* __restrict__ XDi,
    float* __restrict__ ae, float* __restrict__ ai,
    float* __restrict__ Xnge, float* __restrict__ Xngi, float* __restrict__ fluxg)
{
  const float* sVe = VDe+16384; const float* sVi = VDi+16384; const float* wvi = VDi+16512;
  const float* Ge = XDe; const float* Gi = XDi;
  const float* XGe = XDe+8192; const float* XGi = XDi+8192;
  __shared__ float red[64];
  int t=threadIdx.x;
  if (t<64){
    float s1=0.f,s2=0.f,tr=0.f;
    for (int q=0;q<64;q++){
      s1 += S2e[t*64+q]*sVe[q];
      s2 += S2i[t*64+q]*sVi[q];
      tr += XiN[(size_t)q*OUTWC + (NXC-1)]*S2i[q*64+t];
    }
    ae[t]=s1; ai[t]=s2; red[t]=tr*wvi[t];
  }
  __syncthreads();
  if (t==0){ float s=0.f; for(int r=0;r<64;r++) s+=red[r]; fluxg[2]=s; }
  __syncthreads();
  if (t<64){
    float y1=0.f,y2=0.f;
    for (int q=0;q<64;q++){ y1 += Ge[t*64+q]*ae[q]; y2 += Gi[t*64+q]*ai[q]; }
    float f3 = fluxg[2];
    Xnge[t] = 1.0f *DXf*DVf*y1 + f3*XGe[t];
    Xngi[t] = 0.04f*DXf*DVf*y2 + f3*XGi[t];
  }
}

// ---------------- rho ----------------
__global__ __launch_bounds__(256) void k_rho(const float* __restrict__ Xe, int pe,
                                             const float* __restrict__ Xi, int pi,
                                             const float* __restrict__ ae, const float* __restrict__ ai,
                                             float* __restrict__ rho){
  int x = blockIdx.x*256 + threadIdx.x;
  float s = 0.f;
  for (int r=0;r<64;r++) s += ai[r]*Xi[(size_t)r*pi + x] - ae[r]*Xe[(size_t)r*pe + x];
  rho[x] = DVf*s;
}

// ---------------- poisson ----------------
__global__ __launch_bounds__(1024) void k_poisson(const float* __restrict__ rho, float* __restrict__ E){
  __shared__ float wsum[16];
  __shared__ float bsum[16];
  int t = threadIdx.x;
  int base = t*32;
  float loc[32];
  float run = 0.f;
  #pragma unroll
  for (int i=0;i<32;i++){ run += rho[base+i]; loc[i]=run; }
  float v = run;
  for (int off=1; off<64; off<<=1){
    float u = __shfl_up(v, off, 64);
    if ((t&63) >= off) v += u;
  }
  int wave = t>>6;
  if ((t&63)==63) wsum[wave] = v;
  __syncthreads();
  if (t==0){
    float a=0.f;
    for (int w0=0;w0<16;w0++){ float x=wsum[w0]; wsum[w0]=a; a+=x; }
  }
  __syncthreads();
  float offset = wsum[wave] + (v - run);
  float msum = 0.f;
  #pragma unroll
  for (int i=0;i<32;i++){ float e = DXf*(offset + loc[i]); loc[i]=e; msum += e; }
  float rs2 = msum;
  for (int off=32; off>0; off>>=1) rs2 += __shfl_down(rs2, off, 64);
  if ((t&63)==0) bsum[wave]=rs2;
  __syncthreads();
  if (t==0){ float a=0.f; for(int w0=0;w0<16;w0++) a+=bsum[w0]; bsum[0]=a; }
  __syncthreads();
  float mean = bsum[0]/(float)NXC;
  #pragma unroll
  for (int i=0;i<32;i++) E[base+i] = loc[i]-mean;
}

// ---------------- fold K: C-matrices = M @ S^T (per species), packed for kstep ----------------
// C0[r][p] = (1-dt*nu)*S[p][r] + dtdx*sum_q (vmm-vpm)[r][q]*S[p][q]
// CP = dtdx*vpm@S^T, CM = dtdx*vmm@S^T, CL = Vl@S^T, CR = Vr@S^T, w[p] = sum_q sVs[q]*S[p][q]
// PA[(p<<6)+r] = {C0, CP, CM, w[p]}, PB = {CL, CR}
struct FKArg { const float *S, *VD, *Vl, *Vr; float nu; float *PA, *PB; };
__global__ __launch_bounds__(256) void k_foldK(FKArg a0, FKArg a1){
  FKArg A = blockIdx.y ? a1 : a0;
  __shared__ float Sl[64*65];        // Sl[p*65+q] = S[p*64+q]
  __shared__ float Mrow[4][16*65];   // rows r0..r0+15 of vpm,vmm,Vl,Vr
  __shared__ float wv[64];
  int tid = threadIdx.x;
  int r0 = blockIdx.x*16;
  const float* vpm = A.VD + 8192;
  const float* vmm = A.VD + 12288;
  const float* sVs = A.VD + 16384;
  for (int i=tid;i<4096;i+=256) Sl[(i>>6)*65+(i&63)] = A.S[i];
  for (int i=tid;i<1024;i+=256){
    int rr=i>>6, q=i&63; int r=r0+rr;
    Mrow[0][rr*65+q] = vpm[r*64+q];
    Mrow[1][rr*65+q] = vmm[r*64+q];
    Mrow[2][rr*65+q] = A.Vl[r*64+q];
    Mrow[3][rr*65+q] = A.Vr[r*64+q];
  }
  __syncthreads();
  if (tid < 64){
    float s=0.f;
    for (int q=0;q<64;q++) s += sVs[q]*Sl[tid*65+q];
    wv[tid]=s;
  }
  __syncthreads();
  int rr = tid>>4, pp = (tid&15)*4;
  int r = r0+rr;
  const float DTDX = DTf/DXf;
  float c0[4]={0,0,0,0}, cl[4]={0,0,0,0}, cr[4]={0,0,0,0}, cp[4]={0,0,0,0}, cm[4]={0,0,0,0};
  for (int q=0;q<64;q++){
    float vp_ = DTDX*Mrow[0][rr*65+q];
    float vm_ = DTDX*Mrow[1][rr*65+q];
    float vlv = Mrow[2][rr*65+q];
    float vrv = Mrow[3][rr*65+q];
    float w0 = vm_ - vp_;
    #pragma unroll
    for (int k=0;k<4;k++){
      float sv = Sl[(pp+k)*65+q];
      c0[k] += w0*sv;
      cl[k] += vlv*sv;
      cr[k] += vrv*sv;
      cp[k] += vp_*sv;
      cm[k] += vm_*sv;
    }
  }
  float dn = 1.f - DTf*A.nu;
  #pragma unroll
  for (int k=0;k<4;k++){
    int p = pp+k;
    float c0f = c0[k] + dn*Sl[p*65+r];
    int qi = (p<<6) + r;
    float4 pa; pa.x=c0f; pa.y=cp[k]; pa.z=cm[k]; pa.w=wv[p];
    *reinterpret_cast<float4*>(&A.PA[4*qi]) = pa;
    float2 pb; pb.x=cl[k]; pb.y=cr[k];
    *reinterpret_cast<float2*>(&A.PB[2*qi]) = pb;
  }
}

// ---------------- fold L: D-matrices = Z @ S2 (per species), packed for lstep ----------------
// per (r,q): gh=dt(g-h), hg=dt(ht-g), dep=dtdv*ep, dem=dtdv*em, b0=-dt*nu*dx*g-dep+dem
// D0=(I+B0)@S2, DP=DEP@S2, DM=DEM@S2, DGH=GH@S2, DHG=HG@S2
// QA[(p<<6)+r] = {D0, DP, DM, 0}, QB = {DGH, DHG}
struct FLArg { const float *S2, *XD, *ED; float nu; float *QA, *QB; };
__global__ __launch_bounds__(256) void k_foldL(FLArg a0, FLArg a1){
  FLArg A = blockIdx.y ? a1 : a0;
  __shared__ float Sl[64*65];        // Sl[q*65+p] = S2[q*64+p]
  __shared__ float Hl[64*65];        // full H
  int tid = threadIdx.x;
  int r0 = blockIdx.x*16;
  for (int i=tid;i<4096;i+=256){
    Sl[(i>>6)*65+(i&63)] = A.S2[i];
    Hl[(i>>6)*65+(i&63)] = A.XD[4096+i];
  }
  __syncthreads();
  int rr = tid>>4, pp = (tid&15)*4;
  int r = r0+rr;
  const float DTDV = DTf/DVf;
  float d0[4]={0,0,0,0}, dgh[4]={0,0,0,0}, dhg[4]={0,0,0,0}, dp[4]={0,0,0,0}, dm[4]={0,0,0,0};
  for (int q=0;q<64;q++){
    float g  = A.XD[r*64+q];
    float ep = A.ED[r*64+q];
    float em = A.ED[4096 + r*64+q];
    float h  = Hl[r*65+q];
    float ht = Hl[q*65+r];
    float gh = DTf*(g-h), hg = DTf*(ht-g);
    float dep = DTDV*ep, dem = DTDV*em;
    float b0 = -DTf*A.nu*DXf*g - dep + dem;
    #pragma unroll
    for (int k=0;k<4;k++){
      float sv = Sl[q*65+pp+k];
      d0[k]  += b0*sv;
      dgh[k] += gh*sv;
      dhg[k] += hg*sv;
      dp[k]  += dep*sv;
      dm[k]  += dem*sv;
    }
  }
  #pragma unroll
  for (int k=0;k<4;k++){
    int p = pp+k;
    float d0f = d0[k] + Sl[r*65+p];   // identity: + S2[r][p]
    int qi = (p<<6) + r;
    float4 qa; qa.x=d0f; qa.y=dp[k]; qa.z=dm[k]; qa.w=0.f;
    *reinterpret_cast<float4*>(&A.QA[4*qi]) = qa;
    float2 qb; qb.x=dgh[k]; qb.y=dhg[k];
    *reinterpret_cast<float2*>(&A.QB[2*qi]) = qb;
  }
}

// ---------------- K step v10: folded matrices, X staged raw, no phase-1 ----------------
struct KArg { const float *X, *PA, *PB, *VD; float nu, fac; float* Kout; };
__global__ __launch_bounds__(256) void k_kstepf(KArg k0, KArg k1,
    const float* __restrict__ E, const float* __restrict__ gsh, const float* __restrict__ fluxg)
{
  KArg A = blockIdx.y ? k1 : k0;
  __shared__ __align__(16) float Xt[64*36];
  __shared__ float VMs[64];
  int x0 = blockIdx.x*32;
  int tid = threadIdx.x;
  for (int i=tid;i<64*36;i+=256){
    int r=i/36, cc=i%36; int x = x0-1+cc;
    Xt[i] = (cc<34 && x>=0 && x<NXC)? A.X[(size_t)r*NXC+x] : 0.f;
  }
  if (tid<64) VMs[tid]=A.VD[16448+tid];
  __syncthreads();
  int r = tid & 63, w8 = (tid>>6)*8;
  float fo = fluxg[0];
  const float* __restrict__ PA = A.PA;
  const float* __restrict__ PB = A.PB;
  float acc[8], nacc[8], epv[8], emv[8];
  #pragma unroll
  for (int c=0;c<8;c++){
    int x = x0 + w8 + c;
    float Ex = A.fac*E[x];
    epv[c] = DTf*(Ex>0.f?Ex:0.f); emv[c] = DTf*(Ex<0.f?Ex:0.f);
    acc[c]=0.f; nacc[c]=0.f;
  }
  #pragma unroll 2
  for (int p=0;p<64;p++){
    int qi = (p<<6) + r;
    float4 pa = *reinterpret_cast<const float4*>(&PA[4*qi]);
    float2 pb = *reinterpret_cast<const float2*>(&PB[2*qi]);
    const float4 kA = *reinterpret_cast<const float4*>(&Xt[p*36 + w8]);
    const float4 kB = *reinterpret_cast<const float4*>(&Xt[p*36 + w8 + 4]);
    const float2 kC = *reinterpret_cast<const float2*>(&Xt[p*36 + w8 + 8]);
    float kseg[10] = {kA.x,kA.y,kA.z,kA.w,kB.x,kB.y,kB.z,kB.w,kC.x,kC.y};
    #pragma unroll
    for (int c=0;c<8;c++){
      float xv = kseg[c+1];
      float t = pa.x - (epv[c]*pb.x + emv[c]*pb.y);
      acc[c] += t*xv + pa.y*kseg[c] - pa.z*kseg[c+2];
      nacc[c] += pa.w*xv;
    }
  }
  float vmr = VMs[r];
  #pragma unroll
  for (int c=0;c<8;c++){
    int x = x0 + w8 + c;
    float y = acc[c] + DTf*(nacc[c]*DVf*A.nu + fo*gsh[x])*vmr;
    A.Kout[(size_t)r*NXC + x] = y;
  }
}

// ---------------- L step v10: folded matrices, V staged raw, no phase-1 ----------------
struct LArg { const float *V, *QA, *QB, *Xng; float Amax; float* Lout; };
__global__ __launch_bounds__(256) void k_lstepf(LArg l0, LArg l1)
{
  LArg A = blockIdx.y ? l1 : l0;
  __shared__ __align__(16) float Vt[64*36];
  __shared__ float xngs[64];
  int v0 = blockIdx.x*32;
  int tid = threadIdx.x;
  for (int i=tid;i<64*36;i+=256){
    int r=i/36, cc=i%36; int vv = v0-1+cc;
    Vt[i] = (cc<34 && vv>=0 && vv<NVC)? A.V[(size_t)r*NVC+vv] : 0.f;
  }
  if (tid<64) xngs[tid]=A.Xng[tid];
  __syncthreads();
  int r = tid & 63, w8 = (tid>>6)*8;
  const float* __restrict__ QA = A.QA;
  const float* __restrict__ QB = A.QB;
  float fm = sqrtf(A.Amax*INV2PI);
  float acc[8], vpc[8], vmc[8], mvv[8];
  #pragma unroll
  for (int c=0;c<8;c++){
    int vgl = v0 + w8 + c;
    float vs = -VMAXf + (vgl+0.5f)*DVf;
    vpc[c] = vs>0.f?vs:0.f; vmc[c] = vs<0.f?vs:0.f;
    mvv[c] = fm*expf(-0.5f*A.Amax*vs*vs);
    acc[c] = 0.f;
  }
  #pragma unroll 2
  for (int p=0;p<64;p++){
    int qi = (p<<6) + r;
    float4 qa = *reinterpret_cast<const float4*>(&QA[4*qi]);
    float2 qb = *reinterpret_cast<const float2*>(&QB[2*qi]);
    const float4 lA = *reinterpret_cast<const float4*>(&Vt[p*36 + w8]);
    const float4 lB = *reinterpret_cast<const float4*>(&Vt[p*36 + w8 + 4]);
    const float2 lC = *reinterpret_cast<const float2*>(&Vt[p*36 + w8 + 8]);
    float lseg[10] = {lA.x,lA.y,lA.z,lA.w,lB.x,lB.y,lB.z,lB.w,lC.x,lC.y};
    #pragma unroll
    for (int c=0;c<8;c++){
      float t = qa.x - (vpc[c]*qb.x + vmc[c]*qb.y);
      acc[c] += t*lseg[c+1] + qa.y*lseg[c] - qa.z*lseg[c+2];
    }
  }
  float xr = xngs[r];
  #pragma unroll
  for (int c=0;c<8;c++){
    int vgl = v0 + w8 + c;
    float y = acc[c] + DTf*xr*mvv[c];
    A.Lout[(size_t)r*NVC + vgl] = y;
  }
}

// ---------------- S step products ----------------
struct SPArg { const float *S, *XD, *ED, *Vl, *Vr, *VD; float nu; float* P; };
__global__ __launch_bounds__(256) void k_sprod(SPArg ea, SPArg ia){
  SPArg A = blockIdx.z ? ia : ea;
  int p  = blockIdx.y;
  int r0 = blockIdx.x*16;
  __shared__ float Sl[4096];
  __shared__ float Mb[16*65];
  __shared__ float M2[64*65];
  __shared__ float Tt[16*65];
  int tid = threadIdx.x;
  const float* G  = A.XD;
  const float* H  = A.XD + 4096;
  const float* Ep = A.ED;
  const float* Em = A.ED + 4096;
  for (int i=tid;i<4096;i+=256) Sl[i] = A.S[i];
  for (int i=tid;i<1024;i+=256){
    int rr=i>>6, c=i&63, r=r0+rr;
    float m;
    if      (p==0) m = G[r*64+c]-H[r*64+c];
    else if (p==1) m = H[c*64+r]-G[r*64+c];
    else if (p==2) m = Ep[r*64+c];
    else if (p==3) m = Em[r*64+c];
    else           m = G[r*64+c];
    Mb[rr*65+c]=m;
  }
  __syncthreads();
  int rr = tid>>4, b0 = (tid&15)*4;
  float acc[4]={0.f,0.f,0.f,0.f};
  for (int c=0;c<64;c++){
    float m = Mb[rr*65+c];
    #pragma unroll
    for (int k=0;k<4;k++) acc[k] += m*Sl[c*64+b0+k];
  }
  if (p==4){
    float s = A.nu*DXf;
    #pragma unroll
    for (int k=0;k<4;k++) A.P[(size_t)p*4096 + (r0+rr)*64 + b0+k] = s*acc[k];
    return;
  }
  #pragma unroll
  for (int k=0;k<4;k++) Tt[rr*65+b0+k]=acc[k];
  if (p<2){
    const float* src = (p==0)? A.VD+8192 : A.VD+12288;
    for (int i=tid;i<4096;i+=256){ int c=i>>6,b=i&63; M2[c*65+b]=src[i]; }
  } else {
    const float* src = (p==2)? A.Vl : A.Vr;
    for (int i=tid;i<4096;i+=256){ int b=i>>6,c=i&63; M2[c*65+b]=src[i]; }
  }
  __syncthreads();
  float acc2[4]={0.f,0.f,0.f,0.f};
  for (int c=0;c<64;c++){
    float t = Tt[rr*65+c];
    #pragma unroll
    for (int k=0;k<4;k++) acc2[k] += t*M2[c*65+b0+k];
  }
  #pragma unroll
  for (int k=0;k<4;k++) A.P[(size_t)p*4096 + (r0+rr)*64 + b0+k] = acc2[k];
}

// ---------------- S step combine ----------------
__global__ __launch_bounds__(256) void k_scomb(const float* __restrict__ Se, const float* __restrict__ Si,
    const float* __restrict__ P,
    const float* __restrict__ Xnge, const float* __restrict__ Xngi,
    const float* __restrict__ VDe, const float* __restrict__ VDi,
    float* __restrict__ S2e, float* __restrict__ S2i){
  int sp = blockIdx.y;
  int i = blockIdx.x*256 + threadIdx.x;
  const float* S   = sp ? Si : Se;
  const float* Pb  = P + (size_t)sp*5*4096;
  const float* xng = sp ? Xngi : Xnge;
  const float* VMv = (sp ? VDi : VDe) + 16448;
  float* S2 = sp ? S2i : S2e;
  int a=i>>6, b=i&63;
  float s = ((Pb[i] + Pb[4096+i]) + (Pb[8192+i] + Pb[12288+i])) + Pb[16384+i] - xng[a]*VMv[b];
  S2[i] = S[i] + DTf*s;
}

// ---------------- Gram: all-fp32, 128 blocks/species ----------------
__global__ __launch_bounds__(256) void k_gramf(const float* __restrict__ A0, const float* __restrict__ A1,
                                               int n, float* __restrict__ part){
  __shared__ float At[64][65];
  int sp = blockIdx.y;
  const float* A = sp ? A1 : A0;
  int blk = blockIdx.x, nb = gridDim.x;
  int chunk = n/nb;
  int c0b = blk*chunk;
  int tid=threadIdx.x, ta=tid>>4, tb=tid&15, a0=ta*4, b0=tb*4;
  float acc[4][4]={{0}};
  for (int t0=0;t0<chunk;t0+=64){
    int c0=c0b+t0;
    for (int i=tid;i<64*64;i+=256){ int r=i>>6, cc=i&63; At[r][cc]=A[(size_t)r*n + c0+cc]; }
    __syncthreads();
    for (int cc=0;cc<64;cc++){
      float av[4],bv[4];
      #pragma unroll
      for(int k=0;k<4;k++){ av[k]=At[a0+k][cc]; bv[k]=At[b0+k][cc]; }
      #pragma unroll
      for(int ka=0;ka<4;ka++){
        #pragma unroll
        for(int kb=0;kb<4;kb++) acc[ka][kb] += av[ka]*bv[kb];
      }
    }
    __syncthreads();
  }
  float* pb = part + (size_t)(sp*nb+blk)*4096;
  #pragma unroll
  for(int ka=0;ka<4;ka++){
    #pragma unroll
    for(int kb=0;kb<4;kb++) pb[(a0+ka)*64 + b0+kb] = acc[ka][kb];
  }
}

// ---------------- blocked fp32 Cholesky ----------------
__device__ void chol_blk32(float* __restrict__ M, int tid){
  for (int p=0;p<8;p++){
    const int b=8*p;
    if (tid<64){
      float st[8];
      #pragma unroll
      for (int j=0;j<8;j++) st[j] = M[(b+j)*65 + tid];
      #pragma unroll
      for (int kk=0;kk<8;kk++){
        float q[8];
        #pragma unroll
        for (int j=0;j<8;j++) q[j] = __shfl(st[kk], b+j, 64);
        float d = q[kk];
        float rinv = (d > 0.f) ? 1.f/d : 0.f;
        float sk = st[kk];
        #pragma unroll
        for (int j=0;j<8;j++) if (j>kk) st[j] -= q[j]*sk*rinv;
        st[kk] = sk * ((d > 0.f)? rsqrtf(d) : 0.f);
      }
      #pragma unroll
      for (int j=0;j<8;j++) M[(b+j)*65 + tid] = st[j];
    }
    __syncthreads();
    if (b+8 < 64){
      for (int i=(b+8)*64 + tid; i<4096; i+=512){
        int r=i>>6, c=i&63;
        if (c>=r){
          float s=0.f;
          #pragma unroll
          for (int j=0;j<8;j++) s += M[(b+j)*65+r]*M[(b+j)*65+c];
          M[r*65+c] -= s;
        }
      }
    }
    __syncthreads();
  }
}

// ---------------- fused QR: chol + Lw-inverse + block-parallel sign recursion ----------------
struct QArgs {
  const float* Gd; const float* A; int n;
  float scaleS, invQ;
  float* SolveM; float* Sout; int outPitch; int mode;
};
__global__ __launch_bounds__(512) void k_qr(QArgs q0, QArgs q1){
  QArgs Q = (blockIdx.x==0)? q0 : q1;
  __shared__ float Lg[64*65];
  __shared__ float Lw[64*65];
  __shared__ float T[64*65];
  __shared__ float TmpI[448];
  __shared__ float Dv[64];
  int tid = threadIdx.x;
  for (int i=tid;i<4096;i+=512) Lg[(i>>6)*65 + (i&63)] = Q.Gd[i];
  for (int i=tid;i<4096;i+=512){ int c=i>>6, r=i&63; T[r*65+c] = Q.A[(size_t)c*Q.n + r]; }
  __syncthreads();
  chol_blk32(Lg, tid);
  if (tid<64){
    int p=tid>>3, cc=tid&7, b=8*p;
    float wcol[8];
    #pragma unroll
    for (int r=7;r>=0;r--){
      float s = (r==cc)? 1.f : 0.f;
      #pragma unroll
      for (int j=0;j<8;j++) if (j>r) s -= Lg[(b+r)*65 + (b+j)]*wcol[j];
      float dg = Lg[(b+r)*65 + (b+r)];
      wcol[r] = (r<=cc && dg!=0.f)? s/dg : 0.f;
    }
    #pragma unroll
    for (int r=0;r<8;r++) Lw[(b+r)*65 + (b+cc)] = wcol[r];
  }
  __syncthreads();
  for (int d=1; d<8; d++){
    int nb2 = 8-d;
    if (tid < nb2*64){
      int bb=tid>>6, rc=tid&63, r=rc>>3, c=rc&7;
      int p=bb, qb=p+d;
      float s=0.f;
      for (int m=p+1;m<=qb;m++){
        #pragma unroll
        for (int jj=0;jj<8;jj++)
          s += Lg[(8*p+r)*65 + 8*m+jj]*Lw[(8*m+jj)*65 + 8*qb+c];
      }
      TmpI[tid]=s;
    }
    __syncthreads();
    if (tid < nb2*64){
      int bb=tid>>6, rc=tid&63, r=rc>>3, c=rc&7;
      int p=bb, qb=p+d;
      float s=0.f;
      #pragma unroll
      for (int rr=0;rr<8;rr++)
        s += Lw[(8*p+r)*65 + 8*p+rr]*TmpI[(bb<<6)+(rr<<3)+c];
      Lw[(8*p+r)*65 + 8*qb+c] = -s;
    }
    __syncthreads();
  }
  {
    int g = tid>>6, c = tid&63;
    int rbase = g*8;
    for (int k=0;k<64;k++){
      if (tid==k){
        float alpha = T[k*65+k];
        float Ckk = Lg[k*65+k];
        float beta = (alpha>=0.f)? -Ckk : Ckk;
        Dv[k] = (beta>=0.f)? 1.f : -1.f;
      }
      if (rbase+7 > k){
        float alpha = T[k*65+k];
        float Ckk = Lg[k*65+k];
        float beta = (alpha>=0.f)? -Ckk : Ckk;
        float vvh = Ckk*Ckk - alpha*beta;
        float ivv = (vvh>0.f)? __builtin_amdgcn_rcpf(vvh) : 0.f;
        float f = (Lg[k*65+c]*Ckk - beta*T[k*65+c])*ivv;
        if (c > k){
          #pragma unroll
          for (int j=0;j<8;j++){
            int r = rbase+j;
            if (r > k) T[r*65+c] -= f*T[r*65+k];
          }
        }
      }
      __syncthreads();
    }
  }
  for (int i=tid;i<4096;i+=512){
    int r=i>>6, q2=i&63;
    Q.SolveM[i] = (q2<=r)? (Dv[r]*Lw[q2*65+r]*Q.invQ) : 0.f;
    if (Q.mode==0){
      Q.Sout[i] = (q2>=r)? (Dv[r]*Lg[r*65+q2]*Q.scaleS) : 0.f;
    } else {
      Q.Sout[(size_t)r*Q.outPitch + q2] = (r>=q2)? (Dv[q2]*Lg[q2*65+r]*Q.scaleS) : 0.f;
    }
  }
}

// ---------------- Q formation ----------------
__global__ __launch_bounds__(256) void k_qformf(const float* __restrict__ A0, const float* __restrict__ A1,
    int n, const float* __restrict__ M0, const float* __restrict__ M1,
    float* __restrict__ O0, float* __restrict__ O1, int pitch)
{
  int sp = blockIdx.y >> 2;
  const float* A = sp ? A1 : A0;
  const float* M = sp ? M1 : M0;
  float* Out = sp ? O1 : O0;
  int x = blockIdx.x*256 + threadIdx.x;
  int r0 = (blockIdx.y & 3)*16;
  float acc[16];
  #pragma unroll
  for (int rr=0;rr<16;rr++) acc[rr]=0.f;
  for (int q=0;q<64;q++){
    float aq = A[(size_t)q*n + x];
    #pragma unroll
    for (int rr=0;rr<16;rr++) acc[rr] += M[(r0+rr)*64 + q]*aq;
  }
  #pragma unroll
  for (int rr=0;rr<16;rr++) Out[(size_t)(r0+rr)*pitch + x] = acc[rr];
}

// ======================= host =======================
extern "C" void kernel_launch(void* const* d_in, const int* in_sizes, int n_in,
                              void* d_out, int out_size, void* d_ws, size_t ws_size,
                              hipStream_t stream)
{
  (void)in_sizes; (void)n_in; (void)out_size; (void)ws_size;
  const float* Xe = (const float*)d_in[0];
  const float* Se = (const float*)d_in[1];
  const float* Ve = (const float*)d_in[2];
  const float* Xi = (const float*)d_in[3];
  const float* Si = (const float*)d_in[4];
  const float* Vi = (const float*)d_in[5];
  float* out = (float*)d_out;
  float* w = (float*)d_ws;

  size_t o = 0;
  auto alloc = [&](size_t nn){ size_t r=o; o += (nn+63)&~(size_t)63; return r; };
  size_t F_VD = alloc(2*PS_V);
  size_t F_XD = alloc(2*PS_X);
  size_t F_ED = alloc(2*PS_E);
  size_t F_VL_E = alloc(4096), F_VR_E = alloc(4096), F_VL_I = alloc(4096), F_VR_I = alloc(4096);
  size_t F_PA_E = alloc(16384), F_PA_I = alloc(16384);
  size_t F_PB_E = alloc(8192),  F_PB_I = alloc(8192);
  size_t F_QA_E = alloc(16384), F_QA_I = alloc(16384);
  size_t F_QB_E = alloc(8192),  F_QB_I = alloc(8192);
  size_t F_SC_E = alloc(4096), F_SC_I = alloc(4096), F_S2_E = alloc(4096), F_S2_I = alloc(4096);
  size_t F_SOLVE_E = alloc(4096), F_SOLVE_I = alloc(4096);
  size_t F_AE = alloc(64), F_AI = alloc(64), F_XNGE = alloc(64), F_XNGI = alloc(64);
  size_t F_FLUX = alloc(64);
  size_t F_GSH = alloc(NXC);
  size_t F_RHO = alloc(NXC);
  size_t F_E   = alloc(NXC);
  size_t F_KE = alloc((size_t)64*NXC);
  size_t F_KI = alloc((size_t)64*NXC);
  size_t F_LE = F_KE;
  size_t F_LI = F_KI;
  size_t F_PART = alloc(1060864);
  size_t F_GQR = alloc(16384);
  float* Gqr = w + F_GQR;
  float* part = w + F_PART;
  float* vpart = w + F_KE;
  float* xpart = w + F_KE;
  float* epart = w + F_KE;
  float* Pbuf  = w + F_KE;
  const float* VDe = w + F_VD;
  const float* VDi = w + F_VD + PS_V;
  const float* XDe = w + F_XD;
  const float* XDi = w + F_XD + PS_X;
  const float* EDe = w + F_ED;
  const float* EDi = w + F_ED + PS_E;

  float sqDX = sqrtf(DXf), isqDX = 1.f/sqrtf(DXf);
  float sqDV = sqrtf(DVf), isqDV = 1.f/sqrtf(DVf);
  const float NUE = 1.0f, NUI = 0.04f;
  const float FACE = -1.0f, FACI = 1.0f/1836.0f;

  // --- V-derived stats ---
  k_vstatsf<<<dim3(128,2),256,0,stream>>>(Ve, Vi, vpart);
  k_reduce32f<<<dim3((PS_V+255)/256,2),256,0,stream>>>(vpart, 128, PS_V, w+F_VD);
  k_gshape<<<1,1024,0,stream>>>(w+F_GSH);
  k_prep1<<<1,256,0,stream>>>(Ve, Vi, Se, Si, Xi, VDe, VDi,
                              w+F_VL_E, w+F_VR_E, w+F_VL_I, w+F_VR_I,
                              w+F_AE, w+F_AI, w+F_FLUX);
  {
    FKArg fe{Se, VDe, w+F_VL_E, w+F_VR_E, NUE, w+F_PA_E, w+F_PB_E};
    FKArg fi{Si, VDi, w+F_VL_I, w+F_VR_I, NUI, w+F_PA_I, w+F_PB_I};
    k_foldK<<<dim3(4,2),256,0,stream>>>(fe, fi);
  }
  // --- K step ---
  k_rho<<<NXC/256,256,0,stream>>>(Xe, NXC, Xi, NXC, w+F_AE, w+F_AI, w+F_RHO);
  k_poisson<<<1,1024,0,stream>>>(w+F_RHO, w+F_E);
  KArg ke{Xe, w+F_PA_E, w+F_PB_E, VDe, NUE, FACE, w+F_KE};
  KArg ki{Xi, w+F_PA_I, w+F_PB_I, VDi, NUI, FACI, w+F_KI};
  k_kstepf<<<dim3(NXC/32,2),256,0,stream>>>(ke, ki, w+F_E, w+F_GSH, w+F_FLUX);
  // --- QR of K^T ---
  k_gramf<<<dim3(128,2),256,0,stream>>>(w+F_KE, w+F_KI, NXC, part);
  k_reduce32f<<<dim3(16,2),256,0,stream>>>(part, 128, 4096, Gqr);
  {
    QArgs qe{Gqr,        w+F_KE, NXC, sqDX, isqDX, w+F_SOLVE_E, w+F_SC_E, 0, 0};
    QArgs qi{Gqr+4096,   w+F_KI, NXC, sqDX, isqDX, w+F_SOLVE_I, w+F_SC_I, 0, 0};
    k_qr<<<2,512,0,stream>>>(qe, qi);
  }
  k_qformf<<<dim3(NXC/256,8),256,0,stream>>>(w+F_KE, w+F_KI, NXC, w+F_SOLVE_E, w+F_SOLVE_I,
                                             out, out + (size_t)64*OUTWC, OUTWC);
  // --- X stats on new X ---
  k_xstatsf<<<dim3(128,2),256,0,stream>>>(out, out + (size_t)64*OUTWC, OUTWC, w+F_GSH, xpart);
  k_reduce32f<<<dim3((PS_X+255)/256,2),256,0,stream>>>(xpart, 128, PS_X, w+F_XD);
  // --- S step ---
  k_prep2<<<1,256,0,stream>>>(w+F_SC_E, w+F_SC_I, VDe, VDi, out + (size_t)64*OUTWC,
                              XDe, XDi,
                              w+F_AE, w+F_AI, w+F_XNGE, w+F_XNGI, w+F_FLUX);
  k_rho<<<NXC/256,256,0,stream>>>(out, OUTWC, out + (size_t)64*OUTWC, OUTWC, w+F_AE, w+F_AI, w+F_RHO);
  k_poisson<<<1,1024,0,stream>>>(w+F_RHO, w+F_E);
  k_eweightf<<<dim3(128,2),256,0,stream>>>(out, out + (size_t)64*OUTWC, OUTWC, w+F_E, FACE, FACI, epart);
  k_reduce32f<<<dim3((PS_E+255)/256,2),256,0,stream>>>(epart, 128, PS_E, w+F_ED);
  {
    SPArg spe{w+F_SC_E, XDe, EDe, w+F_VL_E, w+F_VR_E, VDe, NUE, Pbuf};
    SPArg spi{w+F_SC_I, XDi, EDi, w+F_VL_I, w+F_VR_I, VDi, NUI, Pbuf + 5*4096};
    k_sprod<<<dim3(4,5,2),256,0,stream>>>(spe, spi);
  }
  k_scomb<<<dim3(16,2),256,0,stream>>>(w+F_SC_E, w+F_SC_I, Pbuf, w+F_XNGE, w+F_XNGI,
                                       VDe, VDi, w+F_S2_E, w+F_S2_I);
  // --- L step ---
  k_prep3<<<1,256,0,stream>>>(w+F_S2_E, w+F_S2_I, VDe, VDi, out + (size_t)64*OUTWC,
                              XDe, XDi,
                              w+F_AE, w+F_AI, w+F_XNGE, w+F_XNGI, w+F_FLUX);
  k_rho<<<NXC/256,256,0,stream>>>(out, OUTWC, out + (size_t)64*OUTWC, OUTWC, w+F_AE, w+F_AI, w+F_RHO);
  k_poisson<<<1,1024,0,stream>>>(w+F_RHO, w+F_E);
  k_eweightf<<<dim3(128,2),256,0,stream>>>(out, out + (size_t)64*OUTWC, OUTWC, w+F_E, FACE, FACI, epart);
  k_reduce32f<<<dim3((PS_E+255)/256,2),256,0,stream>>>(epart, 128, PS_E, w+F_ED);
  {
    FLArg fe{w+F_S2_E, XDe, EDe, NUE, w+F_QA_E, w+F_QB_E};
    FLArg fi{w+F_S2_I, XDi, EDi, NUI, w+F_QA_I, w+F_QB_I};
    k_foldL<<<dim3(4,2),256,0,stream>>>(fe, fi);
  }
  LArg le{Ve, w+F_QA_E, w+F_QB_E, w+F_XNGE, 1.0f,    w+F_LE};
  LArg li{Vi, w+F_QA_I, w+F_QB_I, w+F_XNGI, 1836.0f, w+F_LI};
  k_lstepf<<<dim3(NVC/32,2),256,0,stream>>>(le, li);
  // --- QR of L^T ---
  k_gramf<<<dim3(128,2),256,0,stream>>>(w+F_LE, w+F_LI, NVC, part);
  k_reduce32f<<<dim3(16,2),256,0,stream>>>(part, 128, 4096, Gqr);
  {
    QArgs qe{Gqr,      w+F_LE, NVC, sqDV, isqDV, w+F_SOLVE_E, out + NXC,                        OUTWC, 1};
    QArgs qi{Gqr+4096, w+F_LI, NVC, sqDV, isqDV, w+F_SOLVE_I, out + (size_t)64*OUTWC + NXC,     OUTWC, 1};
    k_qr<<<2,512,0,stream>>>(qe, qi);
  }
  k_qformf<<<dim3(NVC/256,8),256,0,stream>>>(w+F_LE, w+F_LI, NVC, w+F_SOLVE_E, w+F_SOLVE_I,
                                             out + NXC + 64, out + (size_t)64*OUTWC + NXC + 64, OUTWC);
}